// Round 6
// baseline (3604.079 us; speedup 1.0000x reference)
//
#include <hip/hip_runtime.h>
#include <hip/hip_bf16.h>
#include <cstdint>

#define Bb 64
#define Cc 64
#define Tt 2048
#define Hh 128

typedef __fp16 h2   __attribute__((ext_vector_type(2)));
typedef __fp16 f16x8 __attribute__((ext_vector_type(8)));
typedef float  f32x4 __attribute__((ext_vector_type(4)));

union P8 { uint4 u; f16x8 v; h2 p[4]; __fp16 h[8]; };
union P4 { ushort4 u; __fp16 h[4]; };

__device__ __forceinline__ float fsig(float x)  { return 1.0f / (1.0f + __expf(-x)); }
__device__ __forceinline__ float ftanh(float x) { return 1.0f - 2.0f / (__expf(2.0f * x) + 1.0f); }

__device__ __forceinline__ f16x8 cvt8(float4 a, float4 b) {
    P8 u;
    u.p[0] = __builtin_amdgcn_cvt_pkrtz(a.x, a.y);
    u.p[1] = __builtin_amdgcn_cvt_pkrtz(a.z, a.w);
    u.p[2] = __builtin_amdgcn_cvt_pkrtz(b.x, b.y);
    u.p[3] = __builtin_amdgcn_cvt_pkrtz(b.z, b.w);
    return u.v;
}

// ---------------- Kernel 1: MFMA bidirectional LSTM ----------------
// grid 8 = dir*4 + bgroup. block 512 (8 waves). 16 sequences per block.
// Per step: Z^T = Whh @ h^T + Wih @ x_t^T as mfma_f32_16x16x32_f16.
//   M = 512 gate rows (M-subtile m = gate q; wave w owns j in [16w,16w+16)),
//   N = 16 batch, K = 128 (h) + 64 (x).
// A-frags (weights) static in regs: lane provides A[row=l&15][k=kk*32+(l>>4)*8+e].
// B-frags read from LDS: B[k][col=l&15=b].
// C: col=l&15=b, row=4*(l>>4)+r -> gate m for j=16w+4*(l>>4)+r: all 4 gates
// of a (b,j) pair sit in acc[0..3][r] of ONE lane -> activation is lane-local.
__global__ __launch_bounds__(512, 2) void lstm_kernel(
    const float* __restrict__ x,
    const float* __restrict__ Wih_f, const float* __restrict__ Whh_f,
    const float* __restrict__ bih_f, const float* __restrict__ bhh_f,
    const float* __restrict__ Wih_b, const float* __restrict__ Whh_b,
    const float* __restrict__ bih_b, const float* __restrict__ bhh_b,
    __fp16* __restrict__ y)
{
    const int blk = blockIdx.x;
    const int dir = blk >> 2;
    const int bg  = blk & 3;
    const int tid = threadIdx.x;
    const int w   = tid >> 6;      // wave 0..7 -> j in [16w,16w+16)
    const int l   = tid & 63;
    const int col = l & 15;        // N-dim: batch slot b
    const int hi  = l >> 4;        // k-group / row-group

    const float* Wih = dir ? Wih_b : Wih_f;
    const float* Whh = dir ? Whh_b : Whh_f;
    const float* bih = dir ? bih_b : bih_f;
    const float* bhh = dir ? bhh_b : bhh_f;

    // static A-fragments (f16) + bias + c-state
    f16x8 whA[4][4];
    f16x8 wxA[4][2];
    f32x4 biasv[4];
    float cst[4] = {0.0f, 0.0f, 0.0f, 0.0f};
    #pragma unroll
    for (int m = 0; m < 4; ++m) {
        const int rowA = (m << 7) + (w << 4) + col;
        #pragma unroll
        for (int kk = 0; kk < 4; ++kk) {
            const float* p = Whh + (size_t)rowA * 128 + kk * 32 + hi * 8;
            whA[m][kk] = cvt8(*(const float4*)p, *(const float4*)(p + 4));
        }
        #pragma unroll
        for (int kk = 0; kk < 2; ++kk) {
            const float* p = Wih + (size_t)rowA * 64 + kk * 32 + hi * 8;
            wxA[m][kk] = cvt8(*(const float4*)p, *(const float4*)(p + 4));
        }
        #pragma unroll
        for (int r = 0; r < 4; ++r) {
            const int rowC = (m << 7) + (w << 4) + (hi << 2) + r;
            biasv[m][r] = bih[rowC] + bhh[rowC];
        }
    }

    __shared__ __fp16 xsT[32][16][72];    // [tt][b][c]  (b-stride 144B, 16B-aligned)
    __shared__ __fp16 hb[2][16][136];     // [buf][b][j] (b-stride 272B, 16B-aligned)

    for (int i = tid; i < 1088; i += 512) ((unsigned*)&hb[0][0][0])[i] = 0u;

    for (int tile = 0; tile < Tt / 32; ++tile) {
        const int s0 = tile * 32;
        // stage x tile -> xsT (coalesced along t; prev-tile reads done at last barrier)
        #pragma unroll
        for (int it = 0; it < 16; ++it) {
            int i = tid + it * 512;
            int q = i & 7, c = (i >> 3) & 63, b = i >> 9;
            const float* src = x + ((size_t)(bg * 16 + b) * Cc + c) * Tt
                                 + (dir ? (Tt - 1 - s0 - q * 4 - 3) : (s0 + q * 4));
            float4 v = *(const float4*)src;
            const float* pv = (const float*)&v;
            #pragma unroll
            for (int e = 0; e < 4; ++e) {
                int ss = dir ? (q * 4 + 3 - e) : (q * 4 + e);
                xsT[ss][b][c] = (__fp16)pv[e];
            }
        }
        __syncthreads();

        for (int ss = 0; ss < 32; ++ss) {
            const int s   = s0 + ss;
            const int t   = dir ? (Tt - 1 - s) : s;
            const int cur = s & 1, nxt = cur ^ 1;

            P8 hB[4], xB[2];
            #pragma unroll
            for (int kk = 0; kk < 4; ++kk)
                hB[kk].u = *(const uint4*)&hb[cur][col][kk * 32 + hi * 8];
            #pragma unroll
            for (int kk = 0; kk < 2; ++kk)
                xB[kk].u = *(const uint4*)&xsT[ss][col][kk * 32 + hi * 8];

            f32x4 acc[4];
            #pragma unroll
            for (int m = 0; m < 4; ++m) {
                acc[m] = biasv[m];
                #pragma unroll
                for (int kk = 0; kk < 4; ++kk)
                    acc[m] = __builtin_amdgcn_mfma_f32_16x16x32_f16(whA[m][kk], hB[kk].v, acc[m], 0, 0, 0);
                #pragma unroll
                for (int kk = 0; kk < 2; ++kk)
                    acc[m] = __builtin_amdgcn_mfma_f32_16x16x32_f16(wxA[m][kk], xB[kk].v, acc[m], 0, 0, 0);
            }

            P4 hp;
            #pragma unroll
            for (int r = 0; r < 4; ++r) {
                float zi = acc[0][r], zf = acc[1][r], zg = acc[2][r], zo = acc[3][r];
                cst[r] = fsig(zf) * cst[r] + fsig(zi) * ftanh(zg);
                float hh = fsig(zo) * ftanh(cst[r]);
                hp.h[r] = (__fp16)hh;
            }
            *(ushort4*)&hb[nxt][col][(w << 4) + (hi << 2)] = hp.u;
            *(ushort4*)(y + (((size_t)(bg * 16 + col) * Tt + t) * 256
                             + dir * 128 + (w << 4) + (hi << 2))) = hp.u;
            __syncthreads();
        }
    }
}

// ---------------- Kernel 2: attention scores (MFMA) ----------------
// scores[b][t] = Wu . tanh(Wa @ y[b][t] + ba) + bu
// grid (T/64, B), block 512 (8 waves). Z = Y(64x256) @ Wa^T(256x256):
// wave w owns u-cols [32w,32w+32); Wa B-frags in registers (64 VGPR/lane).
__global__ __launch_bounds__(512, 2) void attn_scores_kernel(
    const __fp16* __restrict__ y,
    const float* __restrict__ Wa, const float* __restrict__ ba,
    const float* __restrict__ Wu, const float* __restrict__ bu,
    float* __restrict__ scores)
{
    const int b   = blockIdx.y;
    const int t0  = blockIdx.x * 64;
    const int tid = threadIdx.x;
    const int w   = tid >> 6, l = tid & 63;
    const int col = l & 15, hi = l >> 4;

    __shared__ __fp16 y_lds[64][264];
    __shared__ float red[8][64];

    f16x8 wB[2][8];
    float bav[2], wuv[2];
    #pragma unroll
    for (int ns = 0; ns < 2; ++ns) {
        const int g = (w << 5) + (ns << 4) + col;
        #pragma unroll
        for (int kk = 0; kk < 8; ++kk) {
            const float* p = Wa + (size_t)g * 256 + kk * 32 + hi * 8;
            wB[ns][kk] = cvt8(*(const float4*)p, *(const float4*)(p + 4));
        }
        bav[ns] = ba[g];
        wuv[ns] = Wu[g];
    }

    #pragma unroll
    for (int it = 0; it < 4; ++it) {
        int i = tid + it * 512;
        int tt = i >> 5, c8 = i & 31;
        uint4 v = *(const uint4*)(y + ((size_t)b * Tt + t0 + tt) * 256 + c8 * 8);
        *(uint4*)&y_lds[tt][c8 * 8] = v;
    }
    __syncthreads();

    f32x4 acc[4][2];
    #pragma unroll
    for (int ms = 0; ms < 4; ++ms)
        #pragma unroll
        for (int ns = 0; ns < 2; ++ns) {
            acc[ms][ns][0] = bav[ns]; acc[ms][ns][1] = bav[ns];
            acc[ms][ns][2] = bav[ns]; acc[ms][ns][3] = bav[ns];
        }

    #pragma unroll
    for (int ms = 0; ms < 4; ++ms) {
        #pragma unroll
        for (int kk = 0; kk < 8; ++kk) {
            P8 a;
            a.u = *(const uint4*)&y_lds[(ms << 4) + col][kk * 32 + hi * 8];
            acc[ms][0] = __builtin_amdgcn_mfma_f32_16x16x32_f16(a.v, wB[0][kk], acc[ms][0], 0, 0, 0);
            acc[ms][1] = __builtin_amdgcn_mfma_f32_16x16x32_f16(a.v, wB[1][kk], acc[ms][1], 0, 0, 0);
        }
    }

    #pragma unroll
    for (int ms = 0; ms < 4; ++ms) {
        float pr[4];
        #pragma unroll
        for (int r = 0; r < 4; ++r) {
            pr[r] = wuv[0] * ftanh(acc[ms][0][r]) + wuv[1] * ftanh(acc[ms][1][r]);
            pr[r] += __shfl_xor(pr[r], 1, 64);
            pr[r] += __shfl_xor(pr[r], 2, 64);
            pr[r] += __shfl_xor(pr[r], 4, 64);
            pr[r] += __shfl_xor(pr[r], 8, 64);
        }
        if (col == 0) {
            #pragma unroll
            for (int r = 0; r < 4; ++r)
                red[w][(ms << 4) + (hi << 2) + r] = pr[r];
        }
    }
    __syncthreads();
    if (tid < 64) {
        float ssum = bu[0];
        #pragma unroll
        for (int wv = 0; wv < 8; ++wv) ssum += red[wv][tid];
        scores[(size_t)b * Tt + t0 + tid] = ssum;
    }
}

// ---------------- Kernel 3: softmax + weighted sum ----------------
__global__ __launch_bounds__(256) void attn_out_kernel(
    const __fp16* __restrict__ y,
    const float* __restrict__ scores,
    float* __restrict__ out)
{
    const int b = blockIdx.x;
    const int tid = threadIdx.x;
    const int lane = tid & 63, wid = tid >> 6;
    __shared__ float wls[2048];
    __shared__ float red[4];

    float m = -1e30f;
    for (int t = tid; t < Tt; t += 256) m = fmaxf(m, scores[(size_t)b * Tt + t]);
    #pragma unroll
    for (int off = 32; off >= 1; off >>= 1) m = fmaxf(m, __shfl_xor(m, off, 64));
    if (lane == 0) red[wid] = m;
    __syncthreads();
    m = fmaxf(fmaxf(red[0], red[1]), fmaxf(red[2], red[3]));
    __syncthreads();

    float sum = 0.0f;
    for (int t = tid; t < Tt; t += 256) {
        float e = __expf(scores[(size_t)b * Tt + t] - m);
        wls[t] = e;
        sum += e;
    }
    #pragma unroll
    for (int off = 32; off >= 1; off >>= 1) sum += __shfl_xor(sum, off, 64);
    if (lane == 0) red[wid] = sum;
    __syncthreads();
    const float inv = 1.0f / (red[0] + red[1] + red[2] + red[3]);

    const __fp16* yb = y + (size_t)b * Tt * 256 + tid;
    float acc = 0.0f;
    for (int t = 0; t < Tt; ++t) {
        acc += wls[t] * (float)yb[(size_t)t * 256];
    }
    out[b * 256 + tid] = acc * inv;
}

extern "C" void kernel_launch(void* const* d_in, const int* in_sizes, int n_in,
                              void* d_out, int out_size, void* d_ws, size_t ws_size,
                              hipStream_t stream) {
    const float* x     = (const float*)d_in[0];
    const float* Wih_f = (const float*)d_in[1];
    const float* Whh_f = (const float*)d_in[2];
    const float* bih_f = (const float*)d_in[3];
    const float* bhh_f = (const float*)d_in[4];
    const float* Wih_b = (const float*)d_in[5];
    const float* Whh_b = (const float*)d_in[6];
    const float* bih_b = (const float*)d_in[7];
    const float* bhh_b = (const float*)d_in[8];
    const float* Wa    = (const float*)d_in[9];
    const float* ba    = (const float*)d_in[10];
    const float* Wu    = (const float*)d_in[11];
    const float* bu    = (const float*)d_in[12];
    float* out = (float*)d_out;

    // workspace: y (B*T*256 f16 = 64 MiB) | scores (B*T f32 = 0.5 MiB)
    __fp16* y = (__fp16*)d_ws;
    float* scores = (float*)((char*)d_ws + (size_t)Bb * Tt * 256 * sizeof(__fp16));

    hipLaunchKernelGGL(lstm_kernel, dim3(8), dim3(512), 0, stream,
                       x, Wih_f, Whh_f, bih_f, bhh_f, Wih_b, Whh_b, bih_b, bhh_b, y);
    hipLaunchKernelGGL(attn_scores_kernel, dim3(Tt / 64, Bb), dim3(512), 0, stream,
                       y, Wa, ba, Wu, bu, scores);
    hipLaunchKernelGGL(attn_out_kernel, dim3(Bb), dim3(256), 0, stream, y, scores, out);
}

// Round 7
// 2095.867 us; speedup vs baseline: 1.7196x; 1.7196x over previous
//
#include <hip/hip_runtime.h>
#include <hip/hip_bf16.h>
#include <cstdint>

#define Bb 64
#define Cc 64
#define Tt 2048
#define Hh 128
#define RING 18
#define XS_PLANE 580   // dwords per ss-plane (16*36 + 4 pad): 4*580 % 32 == 16 -> tq-parity bank spread
#define XS_BSTR  36    // dwords per b-row of x tile (72 f16: 64 used + 8 pad)
#define HR_PLANE 1088  // dwords per ring slot (16 * 68)
#define HR_BSTR  68    // dwords per b-row of h ring (136 f16: 128 used + 8 pad)

typedef __fp16 h2    __attribute__((ext_vector_type(2)));
typedef __fp16 f16x8 __attribute__((ext_vector_type(8)));
typedef float  f32x4 __attribute__((ext_vector_type(4)));

union P8 { uint4 u; f16x8 v; h2 p[4]; __fp16 h[8]; };
union P2 { unsigned int u; h2 p; };

#if __has_builtin(__builtin_amdgcn_exp2f)
#define EXP2F(v) __builtin_amdgcn_exp2f(v)
#else
#define EXP2F(v) __expf(0.69314718056f * (v))
#endif
#define RCPF(v) __builtin_amdgcn_rcpf(v)
#define L2E 1.44269504089f

__device__ __forceinline__ float ftanh(float xx) {
    return 1.0f - 2.0f / (__expf(2.0f * xx) + 1.0f);
}

__device__ __forceinline__ f16x8 cvt8s(float4 a, float4 b, float s) {
    P8 u;
    u.p[0] = __builtin_amdgcn_cvt_pkrtz(a.x * s, a.y * s);
    u.p[1] = __builtin_amdgcn_cvt_pkrtz(a.z * s, a.w * s);
    u.p[2] = __builtin_amdgcn_cvt_pkrtz(b.x * s, b.y * s);
    u.p[3] = __builtin_amdgcn_cvt_pkrtz(b.z * s, b.w * s);
    return u.v;
}

// ---------------- Kernel 1: MFMA bidirectional LSTM ----------------
// grid 8 = dir*4 + bgroup, block 512 (8 waves), 16 sequences per block.
// Z^T = Whh@h^T + Wih@x^T via mfma_f32_16x16x32_f16; M=512 gates (M-subtile m
// = gate), N=16 batch, K=192. C layout: col=lane&15=b, row=4*(lane>>4)+r ->
// all 4 gates of one (b,j) live in acc[0..3][r] of one lane (lane-local act).
// Weights pre-scaled by log2e (2*log2e for g-gate) so act uses native exp2+rcp.
// h kept in an 18-slot LDS ring; y flushed once per 16-step tile (no vmem in
// the step loop -> per-step __syncthreads has no vmcnt drain).
__global__ __launch_bounds__(512, 2) void lstm_kernel(
    const float* __restrict__ x,
    const float* __restrict__ Wih_f, const float* __restrict__ Whh_f,
    const float* __restrict__ bih_f, const float* __restrict__ bhh_f,
    const float* __restrict__ Wih_b, const float* __restrict__ Whh_b,
    const float* __restrict__ bih_b, const float* __restrict__ bhh_b,
    __fp16* __restrict__ y)
{
    const int blk = blockIdx.x;
    const int dir = blk >> 2;
    const int bg  = blk & 3;
    const int tid = threadIdx.x;
    const int w   = tid >> 6;      // wave 0..7 -> j in [16w,16w+16)
    const int l   = tid & 63;
    const int col = l & 15;        // N-dim: batch slot
    const int hi  = l >> 4;        // k-group / row-group

    const float* Wih = dir ? Wih_b : Wih_f;
    const float* Whh = dir ? Whh_b : Whh_f;
    const float* bih = dir ? bih_b : bih_f;
    const float* bhh = dir ? bhh_b : bhh_f;

    const float gsc0 = L2E, gsc1 = L2E, gsc2 = 2.0f * L2E, gsc3 = L2E;

    f16x8 whA[4][4];
    f16x8 wxA[4][2];
    float bias[4][4];
    float cst[4] = {0.0f, 0.0f, 0.0f, 0.0f};
    #pragma unroll
    for (int m = 0; m < 4; ++m) {
        const float s = (m == 0) ? gsc0 : (m == 1) ? gsc1 : (m == 2) ? gsc2 : gsc3;
        const int rowA = (m << 7) + (w << 4) + col;
        #pragma unroll
        for (int kk = 0; kk < 4; ++kk) {
            const float* p = Whh + (size_t)rowA * 128 + kk * 32 + hi * 8;
            whA[m][kk] = cvt8s(*(const float4*)p, *(const float4*)(p + 4), s);
        }
        #pragma unroll
        for (int kk = 0; kk < 2; ++kk) {
            const float* p = Wih + (size_t)rowA * 64 + kk * 32 + hi * 8;
            wxA[m][kk] = cvt8s(*(const float4*)p, *(const float4*)(p + 4), s);
        }
        #pragma unroll
        for (int r = 0; r < 4; ++r) {
            const int rowC = (m << 7) + (w << 4) + (hi << 2) + r;
            bias[m][r] = (bih[rowC] + bhh[rowC]) * s;
        }
    }

    __shared__ __align__(16) unsigned int lds_xs[16 * XS_PLANE];
    __shared__ __align__(16) unsigned int lds_hr[RING * HR_PLANE];
    __fp16* xs_h = (__fp16*)lds_xs;

    // zero initial-h ring slot (RING-1)
    for (int i = tid; i < HR_PLANE; i += 512) lds_hr[(RING - 1) * HR_PLANE + i] = 0u;

    const size_t xbase = (size_t)(bg * 16) * Cc * Tt;
    int slp = RING - 1;   // slot holding h before current step
    int slc = 0;          // slot current step writes

    #pragma unroll 1
    for (int tile = 0; tile < Tt / 16; ++tile) {
        const int s0  = tile << 4;
        const int sl0 = slc;   // slot of step s0 (for the flush)

        // ---- stage x tile: coalesced loads (t across lane-quads) ----
        #pragma unroll
        for (int it = 0; it < 8; ++it) {
            int i = tid + (it << 9);
            int tq = i & 3, c = (i >> 2) & 63, b = i >> 8;
            int tb = dir ? (Tt - 4 - s0 - (tq << 2)) : (s0 + (tq << 2));
            float4 v = *(const float4*)(x + xbase + ((size_t)b * Cc + c) * Tt + tb);
            const float* pv = (const float*)&v;
            #pragma unroll
            for (int e = 0; e < 4; ++e) {
                int ss = dir ? ((tq << 2) + 3 - e) : ((tq << 2) + e);
                xs_h[(size_t)(ss * XS_PLANE + b * XS_BSTR) * 2 + c] = (__fp16)pv[e];
            }
        }
        __syncthreads();   // the ONLY sync that drains vmem (stage loads + prev flush)

        // ---- 16 recurrent steps, no vmem ----
        #pragma unroll 1
        for (int ss = 0; ss < 16; ++ss) {
            const unsigned int* hrow = lds_hr + slp * HR_PLANE + col * HR_BSTR;
            P8 hB[4], xB[2];
            #pragma unroll
            for (int kk = 0; kk < 4; ++kk)
                hB[kk].u = *(const uint4*)(hrow + kk * 16 + hi * 4);
            const unsigned int* xrow = lds_xs + ss * XS_PLANE + col * XS_BSTR;
            #pragma unroll
            for (int kk = 0; kk < 2; ++kk)
                xB[kk].u = *(const uint4*)(xrow + kk * 16 + hi * 4);

            f32x4 acc[4];
            #pragma unroll
            for (int m = 0; m < 4; ++m) {
                f32x4 a = {0.0f, 0.0f, 0.0f, 0.0f};
                #pragma unroll
                for (int kk = 0; kk < 4; ++kk)
                    a = __builtin_amdgcn_mfma_f32_16x16x32_f16(whA[m][kk], hB[kk].v, a, 0, 0, 0);
                #pragma unroll
                for (int kk = 0; kk < 2; ++kk)
                    a = __builtin_amdgcn_mfma_f32_16x16x32_f16(wxA[m][kk], xB[kk].v, a, 0, 0, 0);
                acc[m] = a;
            }

            float hhv[4];
            #pragma unroll
            for (int r = 0; r < 4; ++r) {
                float zi = acc[0][r] + bias[0][r];
                float zf = acc[1][r] + bias[1][r];
                float zg = acc[2][r] + bias[2][r];
                float zo = acc[3][r] + bias[3][r];
                float si = RCPF(1.0f + EXP2F(-zi));
                float sf = RCPF(1.0f + EXP2F(-zf));
                float so = RCPF(1.0f + EXP2F(-zo));
                float tg = fmaf(-2.0f, RCPF(1.0f + EXP2F(zg)), 1.0f);
                float c  = fmaf(sf, cst[r], si * tg);
                cst[r] = c;
                float tc = fmaf(-2.0f, RCPF(1.0f + EXP2F(2.0f * L2E * c)), 1.0f);
                hhv[r] = so * tc;
            }
            P2 hp0, hp1;
            hp0.p = __builtin_amdgcn_cvt_pkrtz(hhv[0], hhv[1]);
            hp1.p = __builtin_amdgcn_cvt_pkrtz(hhv[2], hhv[3]);
            uint2 wv; wv.x = hp0.u; wv.y = hp1.u;
            *(uint2*)(lds_hr + slc * HR_PLANE + col * HR_BSTR + (w << 3) + (hi << 1)) = wv;
            __syncthreads();
            slp = slc;
            slc = (slc + 1 == RING) ? 0 : slc + 1;
        }

        // ---- flush y for this tile (coalesced dwordx4; drains at next tile's sync) ----
        #pragma unroll
        for (int it = 0; it < 8; ++it) {
            int i = tid + (it << 9);
            int jc = i & 15, b = (i >> 4) & 15, ss = i >> 8;
            int sl = sl0 + ss; if (sl >= RING) sl -= RING;
            uint4 v = *(const uint4*)(lds_hr + sl * HR_PLANE + b * HR_BSTR + (jc << 2));
            int t = dir ? (Tt - 1 - (s0 + ss)) : (s0 + ss);
            *(uint4*)(y + (((size_t)(bg * 16 + b) * Tt + t) << 8) + dir * 128 + (jc << 3)) = v;
        }
    }
}

// ---------------- Kernel 2: attention scores (MFMA) ----------------
__global__ __launch_bounds__(512, 2) void attn_scores_kernel(
    const __fp16* __restrict__ y,
    const float* __restrict__ Wa, const float* __restrict__ ba,
    const float* __restrict__ Wu, const float* __restrict__ bu,
    float* __restrict__ scores)
{
    const int b   = blockIdx.y;
    const int t0  = blockIdx.x * 64;
    const int tid = threadIdx.x;
    const int w   = tid >> 6, l = tid & 63;
    const int col = l & 15, hi = l >> 4;

    __shared__ __fp16 y_lds[64][264];
    __shared__ float red[8][64];

    f16x8 wB[2][8];
    float bav[2], wuv[2];
    #pragma unroll
    for (int ns = 0; ns < 2; ++ns) {
        const int g = (w << 5) + (ns << 4) + col;
        #pragma unroll
        for (int kk = 0; kk < 8; ++kk) {
            const float* p = Wa + (size_t)g * 256 + kk * 32 + hi * 8;
            wB[ns][kk] = cvt8s(*(const float4*)p, *(const float4*)(p + 4), 1.0f);
        }
        bav[ns] = ba[g];
        wuv[ns] = Wu[g];
    }

    #pragma unroll
    for (int it = 0; it < 4; ++it) {
        int i = tid + it * 512;
        int tt = i >> 5, c8 = i & 31;
        uint4 v = *(const uint4*)(y + ((size_t)b * Tt + t0 + tt) * 256 + c8 * 8);
        *(uint4*)&y_lds[tt][c8 * 8] = v;
    }
    __syncthreads();

    f32x4 acc[4][2];
    #pragma unroll
    for (int ms = 0; ms < 4; ++ms)
        #pragma unroll
        for (int ns = 0; ns < 2; ++ns) {
            acc[ms][ns][0] = bav[ns]; acc[ms][ns][1] = bav[ns];
            acc[ms][ns][2] = bav[ns]; acc[ms][ns][3] = bav[ns];
        }

    #pragma unroll
    for (int ms = 0; ms < 4; ++ms) {
        #pragma unroll
        for (int kk = 0; kk < 8; ++kk) {
            P8 a;
            a.u = *(const uint4*)&y_lds[(ms << 4) + col][kk * 32 + hi * 8];
            acc[ms][0] = __builtin_amdgcn_mfma_f32_16x16x32_f16(a.v, wB[0][kk], acc[ms][0], 0, 0, 0);
            acc[ms][1] = __builtin_amdgcn_mfma_f32_16x16x32_f16(a.v, wB[1][kk], acc[ms][1], 0, 0, 0);
        }
    }

    #pragma unroll
    for (int ms = 0; ms < 4; ++ms) {
        float pr[4];
        #pragma unroll
        for (int r = 0; r < 4; ++r) {
            pr[r] = wuv[0] * ftanh(acc[ms][0][r]) + wuv[1] * ftanh(acc[ms][1][r]);
            pr[r] += __shfl_xor(pr[r], 1, 64);
            pr[r] += __shfl_xor(pr[r], 2, 64);
            pr[r] += __shfl_xor(pr[r], 4, 64);
            pr[r] += __shfl_xor(pr[r], 8, 64);
        }
        if (col == 0) {
            #pragma unroll
            for (int r = 0; r < 4; ++r)
                red[w][(ms << 4) + (hi << 2) + r] = pr[r];
        }
    }
    __syncthreads();
    if (tid < 64) {
        float ssum = bu[0];
        #pragma unroll
        for (int wv = 0; wv < 8; ++wv) ssum += red[wv][tid];
        scores[(size_t)b * Tt + t0 + tid] = ssum;
    }
}

// ---------------- Kernel 3: softmax + weighted sum ----------------
__global__ __launch_bounds__(256) void attn_out_kernel(
    const __fp16* __restrict__ y,
    const float* __restrict__ scores,
    float* __restrict__ out)
{
    const int b = blockIdx.x;
    const int tid = threadIdx.x;
    const int lane = tid & 63, wid = tid >> 6;
    __shared__ float wls[2048];
    __shared__ float red[4];

    float m = -1e30f;
    for (int t = tid; t < Tt; t += 256) m = fmaxf(m, scores[(size_t)b * Tt + t]);
    #pragma unroll
    for (int off = 32; off >= 1; off >>= 1) m = fmaxf(m, __shfl_xor(m, off, 64));
    if (lane == 0) red[wid] = m;
    __syncthreads();
    m = fmaxf(fmaxf(red[0], red[1]), fmaxf(red[2], red[3]));
    __syncthreads();

    float sum = 0.0f;
    for (int t = tid; t < Tt; t += 256) {
        float e = __expf(scores[(size_t)b * Tt + t] - m);
        wls[t] = e;
        sum += e;
    }
    #pragma unroll
    for (int off = 32; off >= 1; off >>= 1) sum += __shfl_xor(sum, off, 64);
    if (lane == 0) red[wid] = sum;
    __syncthreads();
    const float inv = 1.0f / (red[0] + red[1] + red[2] + red[3]);

    const __fp16* yb = y + (size_t)b * Tt * 256 + tid;
    float acc = 0.0f;
    for (int t = 0; t < Tt; ++t) {
        acc += wls[t] * (float)yb[(size_t)t * 256];
    }
    out[b * 256 + tid] = acc * inv;
}

extern "C" void kernel_launch(void* const* d_in, const int* in_sizes, int n_in,
                              void* d_out, int out_size, void* d_ws, size_t ws_size,
                              hipStream_t stream) {
    const float* x     = (const float*)d_in[0];
    const float* Wih_f = (const float*)d_in[1];
    const float* Whh_f = (const float*)d_in[2];
    const float* bih_f = (const float*)d_in[3];
    const float* bhh_f = (const float*)d_in[4];
    const float* Wih_b = (const float*)d_in[5];
    const float* Whh_b = (const float*)d_in[6];
    const float* bih_b = (const float*)d_in[7];
    const float* bhh_b = (const float*)d_in[8];
    const float* Wa    = (const float*)d_in[9];
    const float* ba    = (const float*)d_in[10];
    const float* Wu    = (const float*)d_in[11];
    const float* bu    = (const float*)d_in[12];
    float* out = (float*)d_out;

    // workspace: y (B*T*256 f16 = 64 MiB) | scores (B*T f32 = 0.5 MiB)
    __fp16* y = (__fp16*)d_ws;
    float* scores = (float*)((char*)d_ws + (size_t)Bb * Tt * 256 * sizeof(__fp16));

    hipLaunchKernelGGL(lstm_kernel, dim3(8), dim3(512), 0, stream,
                       x, Wih_f, Whh_f, bih_f, bhh_f, Wih_b, Whh_b, bih_b, bhh_b, y);
    hipLaunchKernelGGL(attn_scores_kernel, dim3(Tt / 64, Bb), dim3(512), 0, stream,
                       y, Wa, ba, Wu, bu, scores);
    hipLaunchKernelGGL(attn_out_kernel, dim3(Bb), dim3(256), 0, stream, y, scores, out);
}